// Round 1
// baseline (77.636 us; speedup 1.0000x reference)
//
#include <hip/hip_runtime.h>
#include <hip/hip_bf16.h>

typedef __attribute__((ext_vector_type(8))) short short8;   // 8 bf16 (4 VGPRs)
typedef __attribute__((ext_vector_type(4))) float f32x4;
typedef unsigned int uint;
typedef __attribute__((ext_vector_type(4))) uint uint4v;    // align 16 -> dwordx4/b128

#define AS1 __attribute__((address_space(1)))
#define AS3 __attribute__((address_space(3)))

// ws: Rp4 [0,1MB) | Qp4 [1MB,1.25MB) | xph [1.25MB, +34.1MB)
#define QB_OFF  (1u << 20)
#define XPH_OFF (1310720u)
// xph byte addr: n*1115136 + row*16896 + col*256 + c*2   (row,col in 0..65, c in 0..127)
// Rp4 NEW: [hg 0..31][p 0..2047]*16B ; at (hg,p): col=p>>3, kgx=(p&7)^(col&7),
//          holds R[col][k=hg*64+kgx*8+e] (k-order: group g=k>>7 window, c=k&127; f=c*16+g)
// Qp4 NEW: [ks 0..7][p 0..2047]*16B ; at (ks,p): col=p>>2, unit=p&3, Q[col][ks*32+unit*8+e]

__device__ __forceinline__ uint bf16r(float f) {
    uint u = __float_as_uint(f);
    u += 0x7FFFu + ((u >> 16) & 1u);
    return u >> 16;
}
__device__ __forceinline__ uint pk2(float lo, float hi) {
    return bf16r(lo) | (bf16r(hi) << 16);
}

// ---------------- prep: NHWC-padded bf16 x (unchanged), K-slab R and Q for LDS-DMA ----------------
__global__ __launch_bounds__(256) void prep_kernel(
    const float* __restrict__ x, const float* __restrict__ Q, const float* __restrict__ R,
    char* __restrict__ Rp4, char* __restrict__ Qp4, char* __restrict__ xph)
{
    const int bid = blockIdx.x, tid = threadIdx.x;
    if (bid < 2048) {                       // transpose: n = bid>>6, h = bid&63
        __shared__ float xt[128 * 65];
        const int n = bid >> 6, h = bid & 63;
        {   // read x[n][c][h][w] coalesced, stage to LDS
            const int c = tid >> 1, half = tid & 1;
            const float4* src = (const float4*)(x + (((size_t)(n * 128 + c) * 64 + h) * 64 + half * 32));
            #pragma unroll
            for (int q = 0; q < 8; ++q) {
                float4 v = src[q];
                float* d = &xt[c * 65 + half * 32 + q * 4];
                d[0] = v.x; d[1] = v.y; d[2] = v.z; d[3] = v.w;
            }
        }
        __syncthreads();
        {   // write xph[n][h+1][w+1][c] (32 channels per thread)
            const int w = tid >> 2, cq = tid & 3;
            uint pw[16];
            #pragma unroll
            for (int m = 0; m < 16; ++m)
                pw[m] = pk2(xt[(cq * 32 + 2 * m) * 65 + w], xt[(cq * 32 + 2 * m + 1) * 65 + w]);
            char* dst = xph + (size_t)n * 1115136 + (size_t)(h + 1) * 16896 + (w + 1) * 256 + cq * 64;
            #pragma unroll
            for (int i = 0; i < 4; ++i) {
                uint4v q4 = { pw[4 * i], pw[4 * i + 1], pw[4 * i + 2], pw[4 * i + 3] };
                *(uint4v*)(dst + i * 16) = q4;
            }
        }
        if (tid < 32) {                      // col borders 0 and 65
            int side = tid >> 4, e = tid & 15;
            uint4v z = {0, 0, 0, 0};
            *(uint4v*)(xph + (size_t)n * 1115136 + (size_t)(h + 1) * 16896 + side * 65 * 256 + e * 16) = z;
        }
        if (h == 0) {                        // row borders 0 and 65
            uint4v z = {0, 0, 0, 0};
            #pragma unroll
            for (int it = 0; it < 9; ++it) {
                int idx = tid + it * 256;
                if (idx < 2112) {
                    int rr = (idx >= 1056) ? 65 : 0;
                    int jj = idx - (rr ? 1056 : 0);
                    int col = jj >> 4, e = jj & 15;
                    *(uint4v*)(xph + (size_t)n * 1115136 + (size_t)rr * 16896 + col * 256 + e * 16) = z;
                }
            }
        }
    } else if (bid < 2304) {                // R -> Rp4[hg][p]  (pre-inverse-swizzled for LDS slab)
        int g = (bid - 2048) * 256 + tid;   // 0..65535
        int hg = g >> 11, p = g & 2047;
        int col = p >> 3;
        int kgx = (p & 7) ^ (col & 7);
        // k = hg*64 + kgx*8 + e ; c = (hg&1)*64 + kgx*8 + e ; f = c*16 + (hg>>1)
        const float* src = R + (size_t)col * 2048 + (((hg & 1) * 64 + kgx * 8) * 16 + (hg >> 1));
        uint pw[4];
        #pragma unroll
        for (int m = 0; m < 4; ++m)
            pw[m] = pk2(src[(2 * m) * 16], src[(2 * m + 1) * 16]);
        uint4v q4 = { pw[0], pw[1], pw[2], pw[3] };
        *(uint4v*)(Rp4 + (size_t)hg * 32768 + p * 16) = q4;
    } else {                                 // Q -> Qp4[ks][p] (linear: 64B-col-stride self-spreads banks)
        int g = (bid - 2304) * 256 + tid;   // 0..16383
        int ks = g >> 11, p = g & 2047;
        int col = p >> 2, unit = p & 3;
        const float4* s = (const float4*)(Q + (size_t)col * 256 + ks * 32 + unit * 8);
        float4 a = s[0], b = s[1];
        uint4v q4 = { pk2(a.x, a.y), pk2(a.z, a.w), pk2(b.x, b.y), pk2(b.z, b.w) };
        *(uint4v*)(Qp4 + (size_t)ks * 32768 + p * 16) = q4;
    }
}

// ---------------- fused: BM=128 x BN=256, 512 thr / 8 waves (2M x 4N, wave 64x64), 1 block/CU ----------------
// B (R) now staged via global_load_lds per HALF-GROUP (32KB, dbuf) instead of per-wave register
// streams: VMEM bytes/group per CU drop 128KB -> 48KB distinct; block B-traffic/FLOP halves (BM=128).
// LDS 128KB: X slabs 2x32KB [0,64K) | B slabs 2x32KB [64K,128K) | ttile 64KB [0,64K) (after gemm1)
//            | Q slabs reuse B region | epilogue ep[2][128][68] f32 (69.6KB) at 0 (after gemm2)
// Ledger (only DMAs use vmcnt): at h issue B(h+1)[4], at even h also X(g+1)[4] (B first).
//   even h<=28: vmcnt(4) drains B(h+1), keeps X(g+1);  otherwise vmcnt(0).
__global__ __launch_bounds__(512, 2) void fused_kernel(
    const char* __restrict__ xph, const char* __restrict__ Rp4,
    const char* __restrict__ Qp4, float* __restrict__ out)
{
    extern __shared__ __align__(16) char lds[];

    const int b0 = blockIdx.x;
    const int b = (b0 & 7) * 32 + (b0 >> 3);    // XCD-contiguous swizzle (256%8==0)
    const int n = b >> 3, vt = b & 7;           // vt: 4 output-row block (r_ov = vt*4 + rh)
    const int tid = threadIdx.x;
    const int wave = tid >> 6, lane = tid & 63;
    const int lr = lane & 15, kg = lane >> 4;
    const int lr7 = lr & 7;
    const int wm = wave >> 2, wn = wave & 3;    // gemm1: rows wm*64.., cols wn*64..

    const char* xbase = xph + (size_t)n * 1115136;

    int pdst[4], xoff[4];
    #pragma unroll
    for (int q = 0; q < 4; ++q) {
        int p = q * 512 + tid;                  // slab linear unit 0..2047
        pdst[q] = p * 16;
        int m = p >> 4, sl = p & 15;            // m: position row of slab, sl: 16B unit
        xoff[q] = (8 * vt + 2 * (m >> 5)) * 16896 + (2 * (m & 31)) * 256 + ((sl ^ (m & 7)) << 4);
    }
    int abase[4], tbase[4];
    #pragma unroll
    for (int mf = 0; mf < 4; ++mf) {
        int m = wm * 64 + mf * 16 + lr;
        abase[mf] = m * 256;                    // X slab row stride 256B
        tbase[mf] = m * 512;                    // ttile row stride 512B
    }
    int bbase[4];
    #pragma unroll
    for (int nf = 0; nf < 4; ++nf) bbase[nf] = (wn * 64 + nf * 16 + lr) * 128;   // B slab col stride 128B
    int qbase[8];                               // gemm2 col map: si=wn>>1, sj=nf>>2, ochalf=wn&1
    #pragma unroll
    for (int nf = 0; nf < 8; ++nf)
        qbase[nf] = ((wn >> 1) * 256 + (nf >> 2) * 128 + (wn & 1) * 64 + (nf & 3) * 16 + lr) * 64;

#define BDMA(hg_, sb_) { _Pragma("unroll") for (int q = 0; q < 4; ++q)                  \
        __builtin_amdgcn_global_load_lds(                                               \
            (const AS1 void*)(Rp4 + (size_t)(hg_) * 32768 + pdst[q]),                   \
            (AS3 void*)(lds + 65536 + (sb_) * 32768 + pdst[q]), 16, 0, 0); }
#define XDMA(g_, sx_) { _Pragma("unroll") for (int q = 0; q < 4; ++q)                   \
        __builtin_amdgcn_global_load_lds(                                               \
            (const AS1 void*)(xbase + xoff[q] + ((g_) >> 2) * 16896 + ((g_) & 3) * 256),\
            (AS3 void*)(lds + (sx_) * 32768 + pdst[q]), 16, 0, 0); }
#define QDMA(ks_, sq_) { _Pragma("unroll") for (int q = 0; q < 4; ++q)                  \
        __builtin_amdgcn_global_load_lds(                                               \
            (const AS1 void*)(Qp4 + (size_t)(ks_) * 32768 + pdst[q]),                   \
            (AS3 void*)(lds + 65536 + (sq_) * 32768 + pdst[q]), 16, 0, 0); }

#define BAR(Nstr) { __builtin_amdgcn_sched_barrier(0);                                  \
        asm volatile("s_waitcnt vmcnt(" Nstr ") lgkmcnt(0)\n\ts_barrier" ::: "memory"); \
        __builtin_amdgcn_sched_barrier(0); }
#define LBAR { __builtin_amdgcn_sched_barrier(0);                                       \
        asm volatile("s_waitcnt lgkmcnt(0)\n\ts_barrier" ::: "memory");                 \
        __builtin_amdgcn_sched_barrier(0); }

    f32x4 acc[4][4];
    #pragma unroll
    for (int i = 0; i < 4; ++i)
        #pragma unroll
        for (int j = 0; j < 4; ++j) acc[i][j] = (f32x4)0.f;

    // prologue: B0,X0,B1,X1 in flight; wait oldest 8 (B0,X0)
    BDMA(0, 0); XDMA(0, 0); BDMA(1, 1); XDMA(1, 1);
    __builtin_amdgcn_sched_barrier(0);
    asm volatile("s_waitcnt vmcnt(8)\n\ts_barrier" ::: "memory");
    __builtin_amdgcn_sched_barrier(0);

    // ---- gemm1: 32 half-groups (hg h = group g*2 + half); X slab per group, B slab per hg ----
    #pragma unroll
    for (int h = 0; h < 32; ++h) {
        if (h >= 1 && h <= 30) BDMA(h + 1, (h + 1) & 1);
        if ((h & 1) == 0 && h >= 2 && h <= 28) XDMA((h >> 1) + 1, ((h >> 1) + 1) & 1);
        if (h == 31) QDMA(0, 0);            // B slab 0 free after h30
        const char* xs = lds + ((h >> 1) & 1) * 32768;
        const char* bs = lds + 65536 + (h & 1) * 32768;
        #pragma unroll
        for (int u = 0; u < 2; ++u) {
            const int ug = (h & 1) * 2 + u; // c-chunk within the group's 128 channels
            short8 af[4], bf[4];
            #pragma unroll
            for (int mf = 0; mf < 4; ++mf)
                af[mf] = *(const short8*)(xs + abase[mf] + (((ug * 4 + kg) ^ lr7) << 4));
            #pragma unroll
            for (int nf = 0; nf < 4; ++nf)
                bf[nf] = *(const short8*)(bs + bbase[nf] + (((u * 4 + kg) ^ lr7) << 4));
            #pragma unroll
            for (int nf = 0; nf < 4; ++nf)
                #pragma unroll
                for (int mf = 0; mf < 4; ++mf)
                    acc[mf][nf] = __builtin_amdgcn_mfma_f32_16x16x32_bf16(af[mf], bf[nf], acc[mf][nf], 0, 0, 0);
        }
        if ((h & 1) == 0 && h <= 28) { BAR("4") } else { BAR("0") }
    }

    // ---- ttile: acc -> bf16 [128][256] at lds+0 (X region dead), XOR-swizzled ----
    #pragma unroll
    for (int mf = 0; mf < 4; ++mf)
        #pragma unroll
        for (int nf = 0; nf < 4; ++nf)
            #pragma unroll
            for (int r = 0; r < 4; ++r) {
                int row = wm * 64 + mf * 16 + kg * 4 + r;
                int col = wn * 64 + nf * 16 + lr;
                *(ushort*)(lds + row * 512 + ((col * 2) ^ ((row & 7) << 4))) =
                    (ushort)bf16r(acc[mf][nf][r]);
            }
    QDMA(1, 1);                              // B slab 1 free after h31
    LBAR                                     // ttile visible; Q1 stays in flight

    // ---- gemm2: Y[128][512] = ttile @ Q^T ; Q slabs (32KB per ks) double-buffered ----
    f32x4 acc2[4][8];
    #pragma unroll
    for (int i = 0; i < 4; ++i)
        #pragma unroll
        for (int j = 0; j < 8; ++j) acc2[i][j] = (f32x4)0.f;
    #pragma unroll
    for (int ks = 0; ks < 8; ++ks) {
        if (ks >= 1 && ks <= 6) QDMA(ks + 1, (ks + 1) & 1);
        const char* qs = lds + 65536 + (ks & 1) * 32768;
        short8 af2[4];
        #pragma unroll
        for (int mf = 0; mf < 4; ++mf)
            af2[mf] = *(const short8*)(lds + tbase[mf] + (((ks * 32 + kg * 8) * 2) ^ (lr7 << 4)));
        #pragma unroll
        for (int nf = 0; nf < 8; ++nf) {
            const short8 bq = *(const short8*)(qs + qbase[nf] + (kg << 4));
            #pragma unroll
            for (int mf = 0; mf < 4; ++mf)
                acc2[mf][nf] = __builtin_amdgcn_mfma_f32_16x16x32_bf16(af2[mf], bq, acc2[mf][nf], 0, 0, 0);
        }
        BAR("0")
    }

    // ---- epilogue: 4 passes (mh = local r_ov); each lane holds 8 w-contiguous f32 -> b128 LDS
    // ep[si][oc][w] f32, row stride 68 (16B-aligned), w-units XOR-swizzled by oc&7 (2-way free)
    const int si = wn >> 1, ochalf = wn & 1;
    #pragma unroll
    for (int mh = 0; mh < 4; ++mh) {
        LBAR
        if (wm == (mh >> 1)) {
            #pragma unroll
            for (int mfh = 0; mfh < 2; ++mfh) {
                const int mf = (mh & 1) * 2 + mfh;
                #pragma unroll
                for (int q = 0; q < 4; ++q) {
                    const int oc = ochalf * 64 + q * 16 + lr;
                    const int ub = si * 34816 + oc * 272 + (((4 * mfh + kg) ^ (oc & 7)) << 5);
                    // w = 32*mfh + 8*kg + 2*reg + sj ; sj=0 -> nf=q, sj=1 -> nf=4+q
                    f32x4 v0 = { acc2[mf][q][0], acc2[mf][4 + q][0], acc2[mf][q][1], acc2[mf][4 + q][1] };
                    f32x4 v1 = { acc2[mf][q][2], acc2[mf][4 + q][2], acc2[mf][q][3], acc2[mf][4 + q][3] };
                    *(f32x4*)(lds + ub) = v0;
                    *(f32x4*)(lds + ub + 16) = v1;
                }
            }
        }
        LBAR
        #pragma unroll
        for (int it = 0; it < 8; ++it) {
            int uidx = it * 512 + tid;
            int w4 = uidx & 15, oc = (uidx >> 4) & 127, sie = uidx >> 11;
            f32x4 v = *(const f32x4*)(lds + sie * 34816 + oc * 272 + ((w4 ^ (2 * (oc & 7))) << 4));
            *(f32x4*)(out + (size_t)n * 524288 + (size_t)oc * 4096
                          + (8 * vt + 2 * mh + sie) * 64 + w4 * 4) = v;
        }
    }
}

extern "C" void kernel_launch(void* const* d_in, const int* in_sizes, int n_in,
                              void* d_out, int out_size, void* d_ws, size_t ws_size,
                              hipStream_t stream) {
    const float* x = (const float*)d_in[0];
    const float* Q = (const float*)d_in[1];
    const float* R = (const float*)d_in[2];
    float* out = (float*)d_out;

    char* ws = (char*)d_ws;
    char* Rp4 = ws;
    char* Qp4 = ws + QB_OFF;
    char* xph = ws + XPH_OFF;

    prep_kernel<<<2368, 256, 0, stream>>>(x, Q, R, Rp4, Qp4, xph);
    fused_kernel<<<256, 512, 131072, stream>>>(xph, Rp4, Qp4, out);
}